// Round 18
// baseline (536.673 us; speedup 1.0000x reference)
//
#include <hip/hip_runtime.h>
#include <stdint.h>

// ---------- types ----------
typedef __bf16 bf16x8 __attribute__((ext_vector_type(8)));
typedef float  f32x4  __attribute__((ext_vector_type(4)));
typedef unsigned short u16x8 __attribute__((ext_vector_type(8)));
typedef const void __attribute__((address_space(1))) gv_t;
typedef void __attribute__((address_space(3))) sv_t;

static __device__ __forceinline__ unsigned short f2bf(float f) {
  unsigned u = __float_as_uint(f);
  u += 0x7fffu + ((u >> 16) & 1u);  // RNE
  return (unsigned short)(u >> 16);
}
static __device__ __forceinline__ float bf2f(unsigned short h) {
  return __uint_as_float(((unsigned)h) << 16);
}
static __device__ __forceinline__ void gload16(const void* g, void* l) {
  __builtin_amdgcn_global_load_lds((gv_t*)g, (sv_t*)l, 16, 0, 0);
}

// ---------- utility ----------
__global__ void k_sentinel(float* out, int n, float val) {
  int t = blockIdx.x * 256 + threadIdx.x;
  if (t < n) out[t] = val;
}

// ---------- prep: zero(deg) + cvtx + all 6 weight transposes, one launch ----
static __device__ __forceinline__ void transW_tile(const float* W, unsigned short* Wt,
                                                   int K, int N, int ld, int kofs,
                                                   int n0, int k0, float (*tile)[33]) {
  int tx = threadIdx.x & 31, ty = threadIdx.x >> 5;  // 32 x 8
#pragma unroll
  for (int r = 0; r < 4; ++r)
    tile[ty + r * 8][tx] = W[(size_t)(k0 + ty + r * 8) * N + n0 + tx];
  __syncthreads();
#pragma unroll
  for (int r = 0; r < 4; ++r)
    Wt[(size_t)(n0 + ty + r * 8) * ld + kofs + k0 + tx] = f2bf(tile[tx][ty + r * 8]);
}

__global__ void k_prep(const float4* __restrict__ x, ushort4* __restrict__ xm,
                       const float* W1l, const float* W1r, const float* W2l,
                       const float* W2r, const float* W3l, const float* W3r,
                       unsigned short* W1t, unsigned short* W2t, unsigned short* W3t,
                       int* deg, int Nn) {
  __shared__ float tile[32][33];
  int bid = blockIdx.x;
  if (bid < 8000) {  // cvtx
    int t = bid * 256 + threadIdx.x;
    int row = t >> 7, c = t & 127;
    float4 v = x[t];
    xm[(size_t)row * 256 + c] = make_ushort4(f2bf(v.x), f2bf(v.y), f2bf(v.z), f2bf(v.w));
    return;
  }
  bid -= 8000;
  if (bid < 2048) {  // W1r -> W1t kofs 0
    transW_tile(W1r, W1t, 512, 4096, 1024, 0, (bid & 127) * 32, (bid >> 7) * 32, tile);
    return;
  }
  bid -= 2048;
  if (bid < 2048) {  // W1l -> W1t kofs 512
    transW_tile(W1l, W1t, 512, 4096, 1024, 512, (bid & 127) * 32, (bid >> 7) * 32, tile);
    return;
  }
  bid -= 2048;
  if (bid < 4096) {  // W2l
    transW_tile(W2l, W2t, 4096, 1024, 4096, 0, (bid & 31) * 32, (bid >> 5) * 32, tile);
    return;
  }
  bid -= 4096;
  if (bid < 4096) {  // W2r
    transW_tile(W2r, W2t + (size_t)1024 * 4096, 4096, 1024, 4096, 0, (bid & 31) * 32,
                (bid >> 5) * 32, tile);
    return;
  }
  bid -= 4096;
  if (bid < 64) {  // W3l
    transW_tile(W3l, W3t, 1024, 64, 1024, 0, (bid & 1) * 32, (bid >> 1) * 32, tile);
    return;
  }
  bid -= 64;
  if (bid < 64) {  // W3r
    transW_tile(W3r, W3t + (size_t)64 * 1024, 1024, 64, 1024, 0, (bid & 1) * 32,
                (bid >> 1) * 32, tile);
    return;
  }
  bid -= 64;
  {  // zero deg
    int t = bid * 256 + threadIdx.x;
    if (t < Nn) deg[t] = 0;
  }
}

// ---------- per-block edge-dtype detect ----------
static __device__ __forceinline__ int detect_i64(const int* ei) {
  __shared__ int sflag;
  if (threadIdx.x < 64) {
    int bad = 0;
#pragma unroll
    for (int j = 0; j < 4; ++j) bad |= ei[2 * (threadIdx.x * 4 + j) + 1];
    unsigned long long m = __ballot(bad != 0);
    if (threadIdx.x == 0) sflag = (m == 0ull) ? 1 : 0;
  }
  __syncthreads();
  return sflag;
}

// ---------- CSR build ----------
__global__ void k_degree(const int* ei, int E, int* deg) {
  int f = detect_i64(ei);
  int t = blockIdx.x * 256 + threadIdx.x;
  if (t < E) {
    int d = f ? ei[2 * (E + t)] : ei[E + t];
    atomicAdd(&deg[d], 1);
  }
}
__global__ void k_scan(const int* deg, int* rp, int* cur, int n) {
  __shared__ int ssum[256];
  int t = threadIdx.x;
  int chunk = (n + 255) >> 8;
  int lo = t * chunk, hi = min(lo + chunk, n);
  int s = 0;
  for (int i = lo; i < hi; ++i) s += deg[i];
  ssum[t] = s;
  __syncthreads();
  if (t == 0) {
    int run = 0;
    for (int i = 0; i < 256; ++i) { int v = ssum[i]; ssum[i] = run; run += v; }
  }
  __syncthreads();
  int run = ssum[t];
  for (int i = lo; i < hi; ++i) { rp[i] = run; cur[i] = run; run += deg[i]; }
  if (t == 255) rp[n] = run;
}
__global__ void k_fill(const int* ei, int E, int* cur, int* col) {
  int f = detect_i64(ei);
  int t = blockIdx.x * 256 + threadIdx.x;
  if (t < E) {
    int s = f ? ei[2 * t] : ei[t];
    int d = f ? ei[2 * (E + t)] : ei[E + t];
    int p = atomicAdd(&cur[d], 1);
    col[p] = s;
  }
}

// ---------- mean aggregation into xm's mean half ----------
__global__ void k_agg(unsigned short* __restrict__ xm, const int* __restrict__ rp,
                      const int* __restrict__ col) {
  int i = blockIdx.x;
  int s = rp[i], e = rp[i + 1];
  float inv = 1.0f / (float)max(e - s, 1);
  int f8 = threadIdx.x & 63;
  int p = threadIdx.x >> 6;
  const u16x8* xm8 = (const u16x8*)xm;
  float acc[8] = {0.f, 0.f, 0.f, 0.f, 0.f, 0.f, 0.f, 0.f};
  for (int n = s + p; n < e; n += 4) {
    u16x8 v = xm8[(size_t)col[n] * 128 + f8];
#pragma unroll
    for (int j = 0; j < 8; ++j) acc[j] += bf2f(v[j]);
  }
  __shared__ float red[3][64][8];
  if (p > 0) {
#pragma unroll
    for (int j = 0; j < 8; ++j) red[p - 1][f8][j] = acc[j];
  }
  __syncthreads();
  if (p == 0) {
    u16x8 o;
#pragma unroll
    for (int j = 0; j < 8; ++j) {
      float v = (acc[j] + red[0][f8][j] + red[1][f8][j] + red[2][f8][j]) * inv;
      o[j] = f2bf(v);
    }
    ((u16x8*)xm)[(size_t)i * 128 + 64 + f8] = o;
  }
}

// ---------- shared GEMM helper macros ----------
#define XCD_SWZ(bnShift_)                                                             \
  const int nwg = gridDim.x;                                                          \
  const int q8 = nwg >> 3, r8 = nwg & 7;                                              \
  const int xcd = blockIdx.x & 7, idx = blockIdx.x >> 3;                              \
  const int wg = (xcd < r8 ? xcd * (q8 + 1) : r8 * (q8 + 1) + (xcd - r8) * q8) + idx; \
  const int bn = wg & ((1 << (bnShift_)) - 1);                                        \
  const int bm = wg >> (bnShift_);

#define VMCNT(NUM) asm volatile("s_waitcnt vmcnt(" #NUM ")" ::: "memory")

#define STAGE_A(BUF, I, K0)                                            \
  gload16(Ap + (size_t)((I) * 64 + rsub) * K + (K0) + sl8,             \
          (char*)&lds[BUF][0][0] + ((I) * 64 + wq * 8) * 128)
#define STAGE_B(BUF, I, K0)                                            \
  gload16(Bp + (size_t)((I) * 64 + rsub) * K + (K0) + sl8,             \
          (char*)&lds[BUF][1][0] + ((I) * 64 + wq * 8) * 128)

#define GEMM256_PRO                                                     \
  STAGE_A(0, 0, 0); STAGE_A(0, 1, 0);                                   \
  STAGE_B(0, 0, 0); STAGE_B(0, 1, 0);                                   \
  STAGE_B(0, 2, 0); STAGE_B(0, 3, 0);                                   \
  STAGE_A(0, 2, 0); STAGE_A(0, 3, 0);                                   \
  STAGE_A(1, 0, 64); STAGE_A(1, 1, 64);                                 \
  STAGE_B(1, 0, 64); STAGE_B(1, 1, 64);                                 \
  STAGE_B(1, 2, 64); STAGE_B(1, 3, 64);                                 \
  STAGE_A(1, 2, 64); STAGE_A(1, 3, 64);                                 \
  VMCNT(8);                                                             \
  __builtin_amdgcn_s_barrier();

#define GEMM256_STAGE_NEXT                                              \
  if (t + 2 < nt) {                                                     \
    STAGE_A(cur, 0, k2); STAGE_A(cur, 1, k2);                           \
    STAGE_B(cur, 0, k2); STAGE_B(cur, 1, k2);                           \
    STAGE_B(cur, 2, k2); STAGE_B(cur, 3, k2);                           \
    STAGE_A(cur, 2, k2); STAGE_A(cur, 3, k2);                           \
  }

#define LOAD_AFR(DST, CUR, QA)                                                          \
  do {                                                                                  \
    const char* baseA = (const char*)&lds[CUR][0][0];                                   \
    _Pragma("unroll") for (int mm = 0; mm < 4; ++mm) {                                  \
      const int rr = ((QA) * 4 + mm) * 32 + wr * 16 + (lane & 15);                      \
      _Pragma("unroll") for (int kk = 0; kk < 2; ++kk)                                  \
          DST[mm][kk] = *(const bf16x8*)(baseA + rr * 128 +                             \
                                         (((kk * 4 + (lane >> 4)) ^ (lane & 7)) << 4)); \
    }                                                                                   \
  } while (0)
#define LOAD_BFR(DST, CUR, QB)                                                          \
  do {                                                                                  \
    const char* baseB = (const char*)&lds[CUR][1][0];                                   \
    _Pragma("unroll") for (int nn = 0; nn < 2; ++nn) {                                  \
      const int cc = ((QB) * 2 + nn) * 64 + wc * 16 + (lane & 15);                      \
      _Pragma("unroll") for (int kk = 0; kk < 2; ++kk)                                  \
          DST[nn][kk] = *(const bf16x8*)(baseB + cc * 128 +                             \
                                         (((kk * 4 + (lane >> 4)) ^ (lane & 7)) << 4)); \
    }                                                                                   \
  } while (0)
#define MFMA_Q(QA, QB, AFR, BFR)                                                        \
  do {                                                                                  \
    _Pragma("unroll") for (int mm = 0; mm < 4; ++mm)                                    \
        _Pragma("unroll") for (int nn = 0; nn < 2; ++nn)                                \
            _Pragma("unroll") for (int kk = 0; kk < 2; ++kk)                            \
                acc[(QA) * 4 + mm][(QB) * 2 + nn] =                                     \
                    __builtin_amdgcn_mfma_f32_16x16x32_bf16(                            \
                        AFR[mm][kk], BFR[nn][kk], acc[(QA) * 4 + mm][(QB) * 2 + nn],    \
                        0, 0, 0);                                                       \
  } while (0)

#define GEMM256_EPI(RELU_, BIAS_)                                       \
  const int row0 = bm * 256 + wr * 16 + ((lane >> 4) << 2);              \
  const int col0 = bn * 256 + wc * 16 + (lane & 15);                     \
  const bool full = (bm + 1) * 256 <= Mreal;                             \
  _Pragma("unroll") for (int m = 0; m < 8; ++m) {                        \
    _Pragma("unroll") for (int n = 0; n < 4; ++n) {                      \
      const int col = col0 + n * 64;                                     \
      float bb = (BIAS_) ? bias[col] : 0.f;                              \
      if (full) {                                                        \
        _Pragma("unroll") for (int r = 0; r < 4; ++r) {                  \
          int row = row0 + m * 32 + r;                                   \
          float v = acc[m][n][r] + bb;                                   \
          if (RELU_) v = fmaxf(v, 0.f);                                  \
          outp[(size_t)row * N + col] = f2bf(v);                         \
        }                                                                \
      } else {                                                           \
        _Pragma("unroll") for (int r = 0; r < 4; ++r) {                  \
          int row = row0 + m * 32 + r;                                   \
          if (row < Mreal) {                                             \
            float v = acc[m][n][r] + bb;                                 \
            if (RELU_) v = fmaxf(v, 0.f);                                \
            outp[(size_t)row * N + col] = f2bf(v);                       \
          }                                                              \
        }                                                                \
      }                                                                  \
    }                                                                    \
  }

// ============ k_gemm256d: dual-role carried-quad (r17-validated) ============
// Role-split by wr so each SIMD hosts one read-first and one MFMA-first wave.
template <bool RELU, bool BIAS>
__global__ __launch_bounds__(512, 1) void k_gemm256d(
    const unsigned short* __restrict__ A, const unsigned short* __restrict__ B,
    const float* __restrict__ bias, unsigned short* __restrict__ outp,
    int Mreal, int N, int K, int bnShift) {
  __shared__ __align__(16) unsigned short lds[2][2][256 * 64];
  const int tid = threadIdx.x;
  const int lane = tid & 63;
  const int wq = tid >> 6;
  const int wr = wq >> 2;
  const int wc = wq & 3;
  XCD_SWZ(bnShift)
  const unsigned short* Ap = A + (size_t)bm * 256 * K;
  const unsigned short* Bp = B + (size_t)bn * 256 * K;
  const int sl8 = ((lane & 7) ^ (lane >> 3)) * 8;
  const int rsub = wq * 8 + (lane >> 3);

  f32x4 acc[8][4];
#pragma unroll
  for (int m = 0; m < 8; ++m)
#pragma unroll
    for (int n = 0; n < 4; ++n) acc[m][n] = (f32x4){0.f, 0.f, 0.f, 0.f};

  GEMM256_PRO

  const int nt = K >> 6;
  if (wr == 0) {
    // ---- role E: r10 exact ----
    bf16x8 a0[4][2], b0[2][2], a1[4][2], b1[2][2];
    LOAD_AFR(a0, 0, 0);
    LOAD_BFR(b0, 0, 0);
#pragma unroll 1
    for (int t = 0; t < nt; ++t) {
      const int cur = t & 1, nxt = cur ^ 1;
      const int k2 = (t + 2) << 6;
      LOAD_AFR(a1, cur, 1);
      LOAD_BFR(b1, cur, 1);
      __builtin_amdgcn_s_setprio(1);
      MFMA_Q(0, 0, a0, b0);
      MFMA_Q(0, 1, a0, b1);
      __builtin_amdgcn_s_setprio(0);
      asm volatile("s_waitcnt vmcnt(0) lgkmcnt(0)" ::: "memory");
      __builtin_amdgcn_s_barrier();
      GEMM256_STAGE_NEXT
      __builtin_amdgcn_s_setprio(1);
      MFMA_Q(1, 0, a1, b0);
      MFMA_Q(1, 1, a1, b1);
      __builtin_amdgcn_s_setprio(0);
      if (t + 1 < nt) {
        LOAD_AFR(a0, nxt, 0);
        LOAD_BFR(b0, nxt, 0);
      }
    }
  } else {
    // ---- role O: mirrored (carry a1,b1; MFMA-first segment entry) ----
    bf16x8 a0[4][2], b0[2][2], a1[4][2], b1[2][2];
    LOAD_AFR(a1, 0, 1);
    LOAD_BFR(b1, 0, 1);
#pragma unroll 1
    for (int t = 0; t < nt; ++t) {
      const int cur = t & 1, nxt = cur ^ 1;
      const int k2 = (t + 2) << 6;
      __builtin_amdgcn_s_setprio(1);
      MFMA_Q(1, 1, a1, b1);          // fully carried -> issues immediately
      __builtin_amdgcn_s_setprio(0);
      LOAD_AFR(a0, cur, 0);
      LOAD_BFR(b0, cur, 0);
      __builtin_amdgcn_s_setprio(1);
      MFMA_Q(1, 0, a1, b0);          // waits on fresh b0 via counted lgkm
      __builtin_amdgcn_s_setprio(0);
      asm volatile("s_waitcnt vmcnt(0) lgkmcnt(0)" ::: "memory");
      __builtin_amdgcn_s_barrier();
      GEMM256_STAGE_NEXT
      __builtin_amdgcn_s_setprio(1);
      MFMA_Q(0, 0, a0, b0);
      MFMA_Q(0, 1, a0, b1);
      __builtin_amdgcn_s_setprio(0);
      if (t + 1 < nt) {
        LOAD_AFR(a1, nxt, 1);
        LOAD_BFR(b1, nxt, 1);
      }
    }
  }

  GEMM256_EPI(RELU, BIAS)
}

// ---------- legacy 128x128 GEMM (proven) for the tiny layer-3 matmul ----------
template <int NF, bool TWO, bool RELU, bool BIAS>
__global__ __launch_bounds__(256) void k_gemm(
    const unsigned short* __restrict__ Am, const unsigned short* __restrict__ Ar,
    const unsigned short* __restrict__ Bl, const unsigned short* __restrict__ Br,
    const float* __restrict__ bias, unsigned short* __restrict__ outp, int N, int K) {
  constexpr int BN = NF * 32;
  __shared__ __align__(16) unsigned short lds[(128 + BN) * 64];
  unsigned short* ldsA = lds;
  unsigned short* ldsB = lds + 128 * 64;

  const int tid = threadIdx.x;
  const int lane = tid & 63;
  const int w = tid >> 6;
  const int wr = w >> 1, wc = w & 1;

  f32x4 zero = {0.f, 0.f, 0.f, 0.f};
  f32x4 acc[4][NF];
#pragma unroll
  for (int m = 0; m < 4; ++m)
#pragma unroll
    for (int n = 0; n < NF; ++n) acc[m][n] = zero;

  const int bm = blockIdx.x, bn = blockIdx.y;
  const int sl_st = (lane & 7) ^ (lane >> 3);

#pragma unroll 1
  for (int pass = 0; pass < (TWO ? 2 : 1); ++pass) {
    const unsigned short* A = (TWO && pass) ? Ar : Am;
    const unsigned short* B = (TWO && pass) ? Br : Bl;
    A += (size_t)bm * 128 * K;
    B += (size_t)bn * BN * K;
#pragma unroll 1
    for (int k0 = 0; k0 < K; k0 += 64) {
      __syncthreads();
#pragma unroll
      for (int q = 0; q < 4; ++q) {
        int rowi = (w * 4 + q) * 8 + (lane >> 3);
        gload16(A + (size_t)rowi * K + k0 + sl_st * 8, (char*)ldsA + (w * 4 + q) * 1024);
      }
#pragma unroll
      for (int q = 0; q < NF; ++q) {
        int rowi = (w * NF + q) * 8 + (lane >> 3);
        gload16(B + (size_t)rowi * K + k0 + sl_st * 8, (char*)ldsB + (w * NF + q) * 1024);
      }
      __syncthreads();
#pragma unroll
      for (int kk = 0; kk < 2; ++kk) {
        int sw = (((kk * 4 + (lane >> 4)) ^ (lane & 7)) << 4);
        bf16x8 af[4], bfr[NF];
#pragma unroll
        for (int m = 0; m < 4; ++m) {
          int r = wr * 64 + m * 16 + (lane & 15);
          af[m] = *(const bf16x8*)((const char*)ldsA + r * 128 + sw);
        }
#pragma unroll
        for (int n = 0; n < NF; ++n) {
          int c = wc * (BN / 2) + n * 16 + (lane & 15);
          bfr[n] = *(const bf16x8*)((const char*)ldsB + c * 128 + sw);
        }
#pragma unroll
        for (int m = 0; m < 4; ++m)
#pragma unroll
          for (int n = 0; n < NF; ++n)
            acc[m][n] = __builtin_amdgcn_mfma_f32_16x16x32_bf16(af[m], bfr[n], acc[m][n], 0, 0, 0);
      }
    }
  }

  const int row0 = bm * 128 + wr * 64;
  const int col0 = bn * BN + wc * (BN / 2);
#pragma unroll
  for (int m = 0; m < 4; ++m) {
#pragma unroll
    for (int n = 0; n < NF; ++n) {
      int col = col0 + n * 16 + (lane & 15);
      float bb = BIAS ? bias[col] : 0.f;
#pragma unroll
      for (int r = 0; r < 4; ++r) {
        int row = row0 + m * 16 + ((lane >> 4) << 2) + r;
        float v = acc[m][n][r] + bb;
        if (RELU) v = fmaxf(v, 0.f);
        outp[(size_t)row * N + col] = f2bf(v);
      }
    }
  }
}

// ---------- layer2 combine: 512 thr = 4 neighbor-parities x 128 lanes -------
__global__ void k_combine2(const unsigned short* __restrict__ Z2, const int* __restrict__ rp,
                           const int* __restrict__ col, const float* __restrict__ bias,
                           unsigned short* __restrict__ h2) {
  int i = blockIdx.x;
  int s = rp[i], e = rp[i + 1];
  float inv = 1.0f / (float)max(e - s, 1);
  int f8 = threadIdx.x & 127;  // 128 ushort8 cover Z2l's 1024 feats
  int p = threadIdx.x >> 7;    // 0..3
  const u16x8* Z28 = (const u16x8*)Z2;
  float acc[8] = {0.f, 0.f, 0.f, 0.f, 0.f, 0.f, 0.f, 0.f};
  for (int n = s + p; n < e; n += 4) {
    u16x8 v = Z28[(size_t)col[n] * 256 + f8];
#pragma unroll
    for (int j = 0; j < 8; ++j) acc[j] += bf2f(v[j]);
  }
  __shared__ float red[3][128][8];
  if (p > 0) {
#pragma unroll
    for (int j = 0; j < 8; ++j) red[p - 1][f8][j] = acc[j];
  }
  __syncthreads();
  if (p == 0) {
    u16x8 r = Z28[(size_t)i * 256 + 128 + f8];
    float4 b4a = ((const float4*)bias)[f8 * 2];
    float4 b4b = ((const float4*)bias)[f8 * 2 + 1];
    float bb[8] = {b4a.x, b4a.y, b4a.z, b4a.w, b4b.x, b4b.y, b4b.z, b4b.w};
    u16x8 o;
#pragma unroll
    for (int j = 0; j < 8; ++j) {
      float v = (acc[j] + red[0][f8][j] + red[1][f8][j] + red[2][f8][j]) * inv +
                bf2f(r[j]) + bb[j];
      o[j] = f2bf(fmaxf(v, 0.f));
    }
    ((u16x8*)h2)[(size_t)i * 128 + f8] = o;
  }
}

// ---------- layer3 combine + log_softmax ----------
__global__ void k_combine3(const unsigned short* __restrict__ Z3, const int* __restrict__ rp,
                           const int* __restrict__ col, const float* __restrict__ bias,
                           float* __restrict__ out) {
  int i = blockIdx.x * 4 + (threadIdx.x >> 6);
  int c = threadIdx.x & 63;
  int s = rp[i], e = rp[i + 1];
  float inv = 1.0f / (float)max(e - s, 1);
  float a = 0.f;
  for (int n = s; n < e; ++n) a += bf2f(Z3[(size_t)col[n] * 128 + c]);
  float v = a * inv + bf2f(Z3[(size_t)i * 128 + 64 + c]) + bias[c];
  float m = v;
#pragma unroll
  for (int o = 1; o < 64; o <<= 1) m = fmaxf(m, __shfl_xor(m, o, 64));
  float t = expf(v - m);
  float sum = t;
#pragma unroll
  for (int o = 1; o < 64; o <<= 1) sum += __shfl_xor(sum, o, 64);
  out[(size_t)i * 64 + c] = (v - m) - logf(sum);
}

// ---------- launch ----------
extern "C" void kernel_launch(void* const* d_in, const int* in_sizes, int n_in,
                              void* d_out, int out_size, void* d_ws, size_t ws_size,
                              hipStream_t stream) {
  const float* x   = (const float*)d_in[0];
  const int*   ei  = (const int*)d_in[1];
  const float* W1l = (const float*)d_in[2];
  const float* b1  = (const float*)d_in[3];
  const float* W1r = (const float*)d_in[4];
  const float* W2l = (const float*)d_in[5];
  const float* b2  = (const float*)d_in[6];
  const float* W2r = (const float*)d_in[7];
  const float* W3l = (const float*)d_in[8];
  const float* b3  = (const float*)d_in[9];
  const float* W3r = (const float*)d_in[10];

  const int Nn = 16000;
  const int E = in_sizes[1] / 2;

  char* p = (char*)d_ws;
  auto carve = [&](size_t bytes) {
    char* r = p;
    p += (bytes + 255) & ~(size_t)255;
    return r;
  };
  int* deg    = (int*)carve((size_t)Nn * 4);
  int* rp     = (int*)carve((size_t)(Nn + 1) * 4);
  int* cur    = (int*)carve((size_t)Nn * 4);
  int* colidx = (int*)carve((size_t)E * 4);
  unsigned short* W2t = (unsigned short*)carve((size_t)2048 * 4096 * 2);
  unsigned short* W3t = (unsigned short*)carve((size_t)128 * 1024 * 2);
  unsigned short* xm  = (unsigned short*)carve((size_t)Nn * 1024 * 2);
  unsigned short* h1  = (unsigned short*)carve((size_t)Nn * 4096 * 2);
  unsigned short* Z2  = (unsigned short*)carve((size_t)Nn * 2048 * 2);
  unsigned short* Z3  = (unsigned short*)carve((size_t)Nn * 128 * 2);
  unsigned short* h2  = xm;
  unsigned short* W1t = Z2;  // consumed by GEMM1 before GEMM2 writes Z2

  size_t need = (size_t)(p - (char*)d_ws);
  if (ws_size < need) {
    k_sentinel<<<(out_size + 255) / 256, 256, 0, stream>>>((float*)d_out, out_size,
                                                           (float)(ws_size >> 20));
    return;
  }

  // 1) prep
  k_prep<<<8000 + 2048 + 2048 + 4096 + 4096 + 64 + 64 + 63, 256, 0, stream>>>(
      (const float4*)x, (ushort4*)xm, W1l, W1r, W2l, W2r, W3l, W3r, W1t, W2t, W3t, deg, Nn);
  // 2-4) CSR
  k_degree<<<(E + 255) / 256, 256, 0, stream>>>(ei, E, deg);
  k_scan<<<1, 256, 0, stream>>>(deg, rp, cur, Nn);
  k_fill<<<(E + 255) / 256, 256, 0, stream>>>(ei, E, cur, colidx);
  // 5) layer-1 aggregation
  k_agg<<<Nn, 256, 0, stream>>>(xm, rp, colidx);
  // 6) GEMM1 (dual-role, r17-validated)
  k_gemm256d<true, true><<<63 * 16, 512, 0, stream>>>(xm, W1t, b1, h1, Nn, 4096, 1024, 4);
  // 7) GEMM2 (dual-role promoted)
  k_gemm256d<false, false><<<63 * 8, 512, 0, stream>>>(h1, W2t, nullptr, Z2, Nn, 2048, 4096, 3);
  // 8) combine2 -> h2 (512 thr, 4-way parity)
  k_combine2<<<Nn, 512, 0, stream>>>(Z2, rp, colidx, b2, h2);
  // 9) GEMM3
  k_gemm<2, false, false, false><<<dim3(125, 2), 256, 0, stream>>>(h2, nullptr, W3t, nullptr,
                                                                   nullptr, Z3, 128, 1024);
  // 10) combine3 + log_softmax
  k_combine3<<<Nn / 4, 256, 0, stream>>>(Z3, rp, colidx, b3, (float*)d_out);

  (void)n_in; (void)out_size;
}

// Round 19
// 533.559 us; speedup vs baseline: 1.0058x; 1.0058x over previous
//
#include <hip/hip_runtime.h>
#include <stdint.h>

// ---------- types ----------
typedef __bf16 bf16x8 __attribute__((ext_vector_type(8)));
typedef float  f32x4  __attribute__((ext_vector_type(4)));
typedef unsigned short u16x8 __attribute__((ext_vector_type(8)));
typedef const void __attribute__((address_space(1))) gv_t;
typedef void __attribute__((address_space(3))) sv_t;

static __device__ __forceinline__ unsigned short f2bf(float f) {
  unsigned u = __float_as_uint(f);
  u += 0x7fffu + ((u >> 16) & 1u);  // RNE
  return (unsigned short)(u >> 16);
}
static __device__ __forceinline__ float bf2f(unsigned short h) {
  return __uint_as_float(((unsigned)h) << 16);
}
static __device__ __forceinline__ void gload16(const void* g, void* l) {
  __builtin_amdgcn_global_load_lds((gv_t*)g, (sv_t*)l, 16, 0, 0);
}

// ---------- utility ----------
__global__ void k_sentinel(float* out, int n, float val) {
  int t = blockIdx.x * 256 + threadIdx.x;
  if (t < n) out[t] = val;
}

// ---------- prep: zero(deg) + cvtx + all 6 weight transposes, one launch ----
static __device__ __forceinline__ void transW_tile(const float* W, unsigned short* Wt,
                                                   int K, int N, int ld, int kofs,
                                                   int n0, int k0, float (*tile)[33]) {
  int tx = threadIdx.x & 31, ty = threadIdx.x >> 5;  // 32 x 8
#pragma unroll
  for (int r = 0; r < 4; ++r)
    tile[ty + r * 8][tx] = W[(size_t)(k0 + ty + r * 8) * N + n0 + tx];
  __syncthreads();
#pragma unroll
  for (int r = 0; r < 4; ++r)
    Wt[(size_t)(n0 + ty + r * 8) * ld + kofs + k0 + tx] = f2bf(tile[tx][ty + r * 8]);
}

__global__ void k_prep(const float4* __restrict__ x, ushort4* __restrict__ xm,
                       const float* W1l, const float* W1r, const float* W2l,
                       const float* W2r, const float* W3l, const float* W3r,
                       unsigned short* W1t, unsigned short* W2t, unsigned short* W3t,
                       int* deg, int Nn) {
  __shared__ float tile[32][33];
  int bid = blockIdx.x;
  if (bid < 8000) {  // cvtx
    int t = bid * 256 + threadIdx.x;
    int row = t >> 7, c = t & 127;
    float4 v = x[t];
    xm[(size_t)row * 256 + c] = make_ushort4(f2bf(v.x), f2bf(v.y), f2bf(v.z), f2bf(v.w));
    return;
  }
  bid -= 8000;
  if (bid < 2048) {  // W1r -> W1t kofs 0
    transW_tile(W1r, W1t, 512, 4096, 1024, 0, (bid & 127) * 32, (bid >> 7) * 32, tile);
    return;
  }
  bid -= 2048;
  if (bid < 2048) {  // W1l -> W1t kofs 512
    transW_tile(W1l, W1t, 512, 4096, 1024, 512, (bid & 127) * 32, (bid >> 7) * 32, tile);
    return;
  }
  bid -= 2048;
  if (bid < 4096) {  // W2l
    transW_tile(W2l, W2t, 4096, 1024, 4096, 0, (bid & 31) * 32, (bid >> 5) * 32, tile);
    return;
  }
  bid -= 4096;
  if (bid < 4096) {  // W2r
    transW_tile(W2r, W2t + (size_t)1024 * 4096, 4096, 1024, 4096, 0, (bid & 31) * 32,
                (bid >> 5) * 32, tile);
    return;
  }
  bid -= 4096;
  if (bid < 64) {  // W3l
    transW_tile(W3l, W3t, 1024, 64, 1024, 0, (bid & 1) * 32, (bid >> 1) * 32, tile);
    return;
  }
  bid -= 64;
  if (bid < 64) {  // W3r
    transW_tile(W3r, W3t + (size_t)64 * 1024, 1024, 64, 1024, 0, (bid & 1) * 32,
                (bid >> 1) * 32, tile);
    return;
  }
  bid -= 64;
  {  // zero deg
    int t = bid * 256 + threadIdx.x;
    if (t < Nn) deg[t] = 0;
  }
}

// ---------- per-block edge-dtype detect ----------
static __device__ __forceinline__ int detect_i64(const int* ei) {
  __shared__ int sflag;
  if (threadIdx.x < 64) {
    int bad = 0;
#pragma unroll
    for (int j = 0; j < 4; ++j) bad |= ei[2 * (threadIdx.x * 4 + j) + 1];
    unsigned long long m = __ballot(bad != 0);
    if (threadIdx.x == 0) sflag = (m == 0ull) ? 1 : 0;
  }
  __syncthreads();
  return sflag;
}

// ---------- CSR build ----------
__global__ void k_degree(const int* ei, int E, int* deg) {
  int f = detect_i64(ei);
  int t = blockIdx.x * 256 + threadIdx.x;
  if (t < E) {
    int d = f ? ei[2 * (E + t)] : ei[E + t];
    atomicAdd(&deg[d], 1);
  }
}
__global__ void k_scan(const int* deg, int* rp, int* cur, int n) {
  __shared__ int ssum[256];
  int t = threadIdx.x;
  int chunk = (n + 255) >> 8;
  int lo = t * chunk, hi = min(lo + chunk, n);
  int s = 0;
  for (int i = lo; i < hi; ++i) s += deg[i];
  ssum[t] = s;
  __syncthreads();
  if (t == 0) {
    int run = 0;
    for (int i = 0; i < 256; ++i) { int v = ssum[i]; ssum[i] = run; run += v; }
  }
  __syncthreads();
  int run = ssum[t];
  for (int i = lo; i < hi; ++i) { rp[i] = run; cur[i] = run; run += deg[i]; }
  if (t == 255) rp[n] = run;
}
__global__ void k_fill(const int* ei, int E, int* cur, int* col) {
  int f = detect_i64(ei);
  int t = blockIdx.x * 256 + threadIdx.x;
  if (t < E) {
    int s = f ? ei[2 * t] : ei[t];
    int d = f ? ei[2 * (E + t)] : ei[E + t];
    int p = atomicAdd(&cur[d], 1);
    col[p] = s;
  }
}

// ---------- mean aggregation into xm's mean half ----------
__global__ void k_agg(unsigned short* __restrict__ xm, const int* __restrict__ rp,
                      const int* __restrict__ col) {
  int i = blockIdx.x;
  int s = rp[i], e = rp[i + 1];
  float inv = 1.0f / (float)max(e - s, 1);
  int f8 = threadIdx.x & 63;
  int p = threadIdx.x >> 6;
  const u16x8* xm8 = (const u16x8*)xm;
  float acc[8] = {0.f, 0.f, 0.f, 0.f, 0.f, 0.f, 0.f, 0.f};
  for (int n = s + p; n < e; n += 4) {
    u16x8 v = xm8[(size_t)col[n] * 128 + f8];
#pragma unroll
    for (int j = 0; j < 8; ++j) acc[j] += bf2f(v[j]);
  }
  __shared__ float red[3][64][8];
  if (p > 0) {
#pragma unroll
    for (int j = 0; j < 8; ++j) red[p - 1][f8][j] = acc[j];
  }
  __syncthreads();
  if (p == 0) {
    u16x8 o;
#pragma unroll
    for (int j = 0; j < 8; ++j) {
      float v = (acc[j] + red[0][f8][j] + red[1][f8][j] + red[2][f8][j]) * inv;
      o[j] = f2bf(v);
    }
    ((u16x8*)xm)[(size_t)i * 128 + 64 + f8] = o;
  }
}

// ---------- shared GEMM helper macros ----------
#define XCD_SWZ(bnShift_)                                                             \
  const int nwg = gridDim.x;                                                          \
  const int q8 = nwg >> 3, r8 = nwg & 7;                                              \
  const int xcd = blockIdx.x & 7, idx = blockIdx.x >> 3;                              \
  const int wg = (xcd < r8 ? xcd * (q8 + 1) : r8 * (q8 + 1) + (xcd - r8) * q8) + idx; \
  const int bn = wg & ((1 << (bnShift_)) - 1);                                        \
  const int bm = wg >> (bnShift_);

#define VMCNT(NUM) asm volatile("s_waitcnt vmcnt(" #NUM ")" ::: "memory")

#define STAGE_A(BUF, I, K0)                                            \
  gload16(Ap + (size_t)((I) * 64 + rsub) * K + (K0) + sl8,             \
          (char*)&lds[BUF][0][0] + ((I) * 64 + wq * 8) * 128)
#define STAGE_B(BUF, I, K0)                                            \
  gload16(Bp + (size_t)((I) * 64 + rsub) * K + (K0) + sl8,             \
          (char*)&lds[BUF][1][0] + ((I) * 64 + wq * 8) * 128)

#define GEMM256_PRO                                                     \
  STAGE_A(0, 0, 0); STAGE_A(0, 1, 0);                                   \
  STAGE_B(0, 0, 0); STAGE_B(0, 1, 0);                                   \
  STAGE_B(0, 2, 0); STAGE_B(0, 3, 0);                                   \
  STAGE_A(0, 2, 0); STAGE_A(0, 3, 0);                                   \
  STAGE_A(1, 0, 64); STAGE_A(1, 1, 64);                                 \
  STAGE_B(1, 0, 64); STAGE_B(1, 1, 64);                                 \
  STAGE_B(1, 2, 64); STAGE_B(1, 3, 64);                                 \
  STAGE_A(1, 2, 64); STAGE_A(1, 3, 64);                                 \
  VMCNT(8);                                                             \
  __builtin_amdgcn_s_barrier();

#define GEMM256_STAGE_NEXT                                              \
  if (t + 2 < nt) {                                                     \
    STAGE_A(cur, 0, k2); STAGE_A(cur, 1, k2);                           \
    STAGE_B(cur, 0, k2); STAGE_B(cur, 1, k2);                           \
    STAGE_B(cur, 2, k2); STAGE_B(cur, 3, k2);                           \
    STAGE_A(cur, 2, k2); STAGE_A(cur, 3, k2);                           \
  }

#define LOAD_AFR(DST, CUR, QA)                                                          \
  do {                                                                                  \
    const char* baseA = (const char*)&lds[CUR][0][0];                                   \
    _Pragma("unroll") for (int mm = 0; mm < 4; ++mm) {                                  \
      const int rr = ((QA) * 4 + mm) * 32 + wr * 16 + (lane & 15);                      \
      _Pragma("unroll") for (int kk = 0; kk < 2; ++kk)                                  \
          DST[mm][kk] = *(const bf16x8*)(baseA + rr * 128 +                             \
                                         (((kk * 4 + (lane >> 4)) ^ (lane & 7)) << 4)); \
    }                                                                                   \
  } while (0)
#define LOAD_BFR(DST, CUR, QB)                                                          \
  do {                                                                                  \
    const char* baseB = (const char*)&lds[CUR][1][0];                                   \
    _Pragma("unroll") for (int nn = 0; nn < 2; ++nn) {                                  \
      const int cc = ((QB) * 2 + nn) * 64 + wc * 16 + (lane & 15);                      \
      _Pragma("unroll") for (int kk = 0; kk < 2; ++kk)                                  \
          DST[nn][kk] = *(const bf16x8*)(baseB + cc * 128 +                             \
                                         (((kk * 4 + (lane >> 4)) ^ (lane & 7)) << 4)); \
    }                                                                                   \
  } while (0)
#define MFMA_Q(QA, QB, AFR, BFR)                                                        \
  do {                                                                                  \
    _Pragma("unroll") for (int mm = 0; mm < 4; ++mm)                                    \
        _Pragma("unroll") for (int nn = 0; nn < 2; ++nn)                                \
            _Pragma("unroll") for (int kk = 0; kk < 2; ++kk)                            \
                acc[(QA) * 4 + mm][(QB) * 2 + nn] =                                     \
                    __builtin_amdgcn_mfma_f32_16x16x32_bf16(                            \
                        AFR[mm][kk], BFR[nn][kk], acc[(QA) * 4 + mm][(QB) * 2 + nn],    \
                        0, 0, 0);                                                       \
  } while (0)

#define GEMM256_EPI(RELU_, BIAS_)                                       \
  const int row0 = bm * 256 + wr * 16 + ((lane >> 4) << 2);              \
  const int col0 = bn * 256 + wc * 16 + (lane & 15);                     \
  const bool full = (bm + 1) * 256 <= Mreal;                             \
  _Pragma("unroll") for (int m = 0; m < 8; ++m) {                        \
    _Pragma("unroll") for (int n = 0; n < 4; ++n) {                      \
      const int col = col0 + n * 64;                                     \
      float bb = (BIAS_) ? bias[col] : 0.f;                              \
      if (full) {                                                        \
        _Pragma("unroll") for (int r = 0; r < 4; ++r) {                  \
          int row = row0 + m * 32 + r;                                   \
          float v = acc[m][n][r] + bb;                                   \
          if (RELU_) v = fmaxf(v, 0.f);                                  \
          outp[(size_t)row * N + col] = f2bf(v);                         \
        }                                                                \
      } else {                                                           \
        _Pragma("unroll") for (int r = 0; r < 4; ++r) {                  \
          int row = row0 + m * 32 + r;                                   \
          if (row < Mreal) {                                             \
            float v = acc[m][n][r] + bb;                                 \
            if (RELU_) v = fmaxf(v, 0.f);                                \
            outp[(size_t)row * N + col] = f2bf(v);                       \
          }                                                              \
        }                                                                \
      }                                                                  \
    }                                                                    \
  }

// ============ k_gemm256d: dual-role carried-quad (validated r17 GEMM1, r18 GEMM2)
// Role-split by wr so each SIMD hosts one read-first and one MFMA-first wave.
template <bool RELU, bool BIAS>
__global__ __launch_bounds__(512, 1) void k_gemm256d(
    const unsigned short* __restrict__ A, const unsigned short* __restrict__ B,
    const float* __restrict__ bias, unsigned short* __restrict__ outp,
    int Mreal, int N, int K, int bnShift) {
  __shared__ __align__(16) unsigned short lds[2][2][256 * 64];
  const int tid = threadIdx.x;
  const int lane = tid & 63;
  const int wq = tid >> 6;
  const int wr = wq >> 2;
  const int wc = wq & 3;
  XCD_SWZ(bnShift)
  const unsigned short* Ap = A + (size_t)bm * 256 * K;
  const unsigned short* Bp = B + (size_t)bn * 256 * K;
  const int sl8 = ((lane & 7) ^ (lane >> 3)) * 8;
  const int rsub = wq * 8 + (lane >> 3);

  f32x4 acc[8][4];
#pragma unroll
  for (int m = 0; m < 8; ++m)
#pragma unroll
    for (int n = 0; n < 4; ++n) acc[m][n] = (f32x4){0.f, 0.f, 0.f, 0.f};

  GEMM256_PRO

  const int nt = K >> 6;
  if (wr == 0) {
    // ---- role E: r10 exact ----
    bf16x8 a0[4][2], b0[2][2], a1[4][2], b1[2][2];
    LOAD_AFR(a0, 0, 0);
    LOAD_BFR(b0, 0, 0);
#pragma unroll 1
    for (int t = 0; t < nt; ++t) {
      const int cur = t & 1, nxt = cur ^ 1;
      const int k2 = (t + 2) << 6;
      LOAD_AFR(a1, cur, 1);
      LOAD_BFR(b1, cur, 1);
      __builtin_amdgcn_s_setprio(1);
      MFMA_Q(0, 0, a0, b0);
      MFMA_Q(0, 1, a0, b1);
      __builtin_amdgcn_s_setprio(0);
      asm volatile("s_waitcnt vmcnt(0) lgkmcnt(0)" ::: "memory");
      __builtin_amdgcn_s_barrier();
      GEMM256_STAGE_NEXT
      __builtin_amdgcn_s_setprio(1);
      MFMA_Q(1, 0, a1, b0);
      MFMA_Q(1, 1, a1, b1);
      __builtin_amdgcn_s_setprio(0);
      if (t + 1 < nt) {
        LOAD_AFR(a0, nxt, 0);
        LOAD_BFR(b0, nxt, 0);
      }
    }
  } else {
    // ---- role O: mirrored (carry a1,b1; MFMA-first segment entry) ----
    bf16x8 a0[4][2], b0[2][2], a1[4][2], b1[2][2];
    LOAD_AFR(a1, 0, 1);
    LOAD_BFR(b1, 0, 1);
#pragma unroll 1
    for (int t = 0; t < nt; ++t) {
      const int cur = t & 1, nxt = cur ^ 1;
      const int k2 = (t + 2) << 6;
      __builtin_amdgcn_s_setprio(1);
      MFMA_Q(1, 1, a1, b1);          // fully carried -> issues immediately
      __builtin_amdgcn_s_setprio(0);
      LOAD_AFR(a0, cur, 0);
      LOAD_BFR(b0, cur, 0);
      __builtin_amdgcn_s_setprio(1);
      MFMA_Q(1, 0, a1, b0);          // waits on fresh b0 via counted lgkm
      __builtin_amdgcn_s_setprio(0);
      asm volatile("s_waitcnt vmcnt(0) lgkmcnt(0)" ::: "memory");
      __builtin_amdgcn_s_barrier();
      GEMM256_STAGE_NEXT
      __builtin_amdgcn_s_setprio(1);
      MFMA_Q(0, 0, a0, b0);
      MFMA_Q(0, 1, a0, b1);
      __builtin_amdgcn_s_setprio(0);
      if (t + 1 < nt) {
        LOAD_AFR(a1, nxt, 1);
        LOAD_BFR(b1, nxt, 1);
      }
    }
  }

  GEMM256_EPI(RELU, BIAS)
}

// ---------- legacy 128x128 GEMM (proven) for the tiny layer-3 matmul ----------
template <int NF, bool TWO, bool RELU, bool BIAS>
__global__ __launch_bounds__(256) void k_gemm(
    const unsigned short* __restrict__ Am, const unsigned short* __restrict__ Ar,
    const unsigned short* __restrict__ Bl, const unsigned short* __restrict__ Br,
    const float* __restrict__ bias, unsigned short* __restrict__ outp, int N, int K) {
  constexpr int BN = NF * 32;
  __shared__ __align__(16) unsigned short lds[(128 + BN) * 64];
  unsigned short* ldsA = lds;
  unsigned short* ldsB = lds + 128 * 64;

  const int tid = threadIdx.x;
  const int lane = tid & 63;
  const int w = tid >> 6;
  const int wr = w >> 1, wc = w & 1;

  f32x4 zero = {0.f, 0.f, 0.f, 0.f};
  f32x4 acc[4][NF];
#pragma unroll
  for (int m = 0; m < 4; ++m)
#pragma unroll
    for (int n = 0; n < NF; ++n) acc[m][n] = zero;

  const int bm = blockIdx.x, bn = blockIdx.y;
  const int sl_st = (lane & 7) ^ (lane >> 3);

#pragma unroll 1
  for (int pass = 0; pass < (TWO ? 2 : 1); ++pass) {
    const unsigned short* A = (TWO && pass) ? Ar : Am;
    const unsigned short* B = (TWO && pass) ? Br : Bl;
    A += (size_t)bm * 128 * K;
    B += (size_t)bn * BN * K;
#pragma unroll 1
    for (int k0 = 0; k0 < K; k0 += 64) {
      __syncthreads();
#pragma unroll
      for (int q = 0; q < 4; ++q) {
        int rowi = (w * 4 + q) * 8 + (lane >> 3);
        gload16(A + (size_t)rowi * K + k0 + sl_st * 8, (char*)ldsA + (w * 4 + q) * 1024);
      }
#pragma unroll
      for (int q = 0; q < NF; ++q) {
        int rowi = (w * NF + q) * 8 + (lane >> 3);
        gload16(B + (size_t)rowi * K + k0 + sl_st * 8, (char*)ldsB + (w * NF + q) * 1024);
      }
      __syncthreads();
#pragma unroll
      for (int kk = 0; kk < 2; ++kk) {
        int sw = (((kk * 4 + (lane >> 4)) ^ (lane & 7)) << 4);
        bf16x8 af[4], bfr[NF];
#pragma unroll
        for (int m = 0; m < 4; ++m) {
          int r = wr * 64 + m * 16 + (lane & 15);
          af[m] = *(const bf16x8*)((const char*)ldsA + r * 128 + sw);
        }
#pragma unroll
        for (int n = 0; n < NF; ++n) {
          int c = wc * (BN / 2) + n * 16 + (lane & 15);
          bfr[n] = *(const bf16x8*)((const char*)ldsB + c * 128 + sw);
        }
#pragma unroll
        for (int m = 0; m < 4; ++m)
#pragma unroll
          for (int n = 0; n < NF; ++n)
            acc[m][n] = __builtin_amdgcn_mfma_f32_16x16x32_bf16(af[m], bfr[n], acc[m][n], 0, 0, 0);
      }
    }
  }

  const int row0 = bm * 128 + wr * 64;
  const int col0 = bn * BN + wc * (BN / 2);
#pragma unroll
  for (int m = 0; m < 4; ++m) {
#pragma unroll
    for (int n = 0; n < NF; ++n) {
      int col = col0 + n * 16 + (lane & 15);
      float bb = BIAS ? bias[col] : 0.f;
#pragma unroll
      for (int r = 0; r < 4; ++r) {
        int row = row0 + m * 16 + ((lane >> 4) << 2) + r;
        float v = acc[m][n][r] + bb;
        if (RELU) v = fmaxf(v, 0.f);
        outp[(size_t)row * N + col] = f2bf(v);
      }
    }
  }
}

// ---------- layer2 combine: 256 thr = 2 neighbor-parities x 128 lanes -------
// (r14/r17-validated version; r18's 4-way parity regressed ~6 us: avg degree
// ~8 leaves each parity only ~2 gather iters, LDS-reduce overhead dominates.)
__global__ void k_combine2(const unsigned short* __restrict__ Z2, const int* __restrict__ rp,
                           const int* __restrict__ col, const float* __restrict__ bias,
                           unsigned short* __restrict__ h2) {
  int i = blockIdx.x;
  int s = rp[i], e = rp[i + 1];
  float inv = 1.0f / (float)max(e - s, 1);
  int f8 = threadIdx.x & 127;  // 128 ushort8 cover Z2l's 1024 feats
  int p = threadIdx.x >> 7;    // 0..1
  const u16x8* Z28 = (const u16x8*)Z2;
  float acc[8] = {0.f, 0.f, 0.f, 0.f, 0.f, 0.f, 0.f, 0.f};
  for (int n = s + p; n < e; n += 2) {
    u16x8 v = Z28[(size_t)col[n] * 256 + f8];
#pragma unroll
    for (int j = 0; j < 8; ++j) acc[j] += bf2f(v[j]);
  }
  __shared__ float red[128][8];
  if (p == 1) {
#pragma unroll
    for (int j = 0; j < 8; ++j) red[f8][j] = acc[j];
  }
  __syncthreads();
  if (p == 0) {
    u16x8 r = Z28[(size_t)i * 256 + 128 + f8];
    float4 b4a = ((const float4*)bias)[f8 * 2];
    float4 b4b = ((const float4*)bias)[f8 * 2 + 1];
    float bb[8] = {b4a.x, b4a.y, b4a.z, b4a.w, b4b.x, b4b.y, b4b.z, b4b.w};
    u16x8 o;
#pragma unroll
    for (int j = 0; j < 8; ++j) {
      float v = (acc[j] + red[f8][j]) * inv + bf2f(r[j]) + bb[j];
      o[j] = f2bf(fmaxf(v, 0.f));
    }
    ((u16x8*)h2)[(size_t)i * 128 + f8] = o;
  }
}

// ---------- layer3 combine + log_softmax ----------
__global__ void k_combine3(const unsigned short* __restrict__ Z3, const int* __restrict__ rp,
                           const int* __restrict__ col, const float* __restrict__ bias,
                           float* __restrict__ out) {
  int i = blockIdx.x * 4 + (threadIdx.x >> 6);
  int c = threadIdx.x & 63;
  int s = rp[i], e = rp[i + 1];
  float inv = 1.0f / (float)max(e - s, 1);
  float a = 0.f;
  for (int n = s; n < e; ++n) a += bf2f(Z3[(size_t)col[n] * 128 + c]);
  float v = a * inv + bf2f(Z3[(size_t)i * 128 + 64 + c]) + bias[c];
  float m = v;
#pragma unroll
  for (int o = 1; o < 64; o <<= 1) m = fmaxf(m, __shfl_xor(m, o, 64));
  float t = expf(v - m);
  float sum = t;
#pragma unroll
  for (int o = 1; o < 64; o <<= 1) sum += __shfl_xor(sum, o, 64);
  out[(size_t)i * 64 + c] = (v - m) - logf(sum);
}

// ---------- launch ----------
extern "C" void kernel_launch(void* const* d_in, const int* in_sizes, int n_in,
                              void* d_out, int out_size, void* d_ws, size_t ws_size,
                              hipStream_t stream) {
  const float* x   = (const float*)d_in[0];
  const int*   ei  = (const int*)d_in[1];
  const float* W1l = (const float*)d_in[2];
  const float* b1  = (const float*)d_in[3];
  const float* W1r = (const float*)d_in[4];
  const float* W2l = (const float*)d_in[5];
  const float* b2  = (const float*)d_in[6];
  const float* W2r = (const float*)d_in[7];
  const float* W3l = (const float*)d_in[8];
  const float* b3  = (const float*)d_in[9];
  const float* W3r = (const float*)d_in[10];

  const int Nn = 16000;
  const int E = in_sizes[1] / 2;

  char* p = (char*)d_ws;
  auto carve = [&](size_t bytes) {
    char* r = p;
    p += (bytes + 255) & ~(size_t)255;
    return r;
  };
  int* deg    = (int*)carve((size_t)Nn * 4);
  int* rp     = (int*)carve((size_t)(Nn + 1) * 4);
  int* cur    = (int*)carve((size_t)Nn * 4);
  int* colidx = (int*)carve((size_t)E * 4);
  unsigned short* W2t = (unsigned short*)carve((size_t)2048 * 4096 * 2);
  unsigned short* W3t = (unsigned short*)carve((size_t)128 * 1024 * 2);
  unsigned short* xm  = (unsigned short*)carve((size_t)Nn * 1024 * 2);
  unsigned short* h1  = (unsigned short*)carve((size_t)Nn * 4096 * 2);
  unsigned short* Z2  = (unsigned short*)carve((size_t)Nn * 2048 * 2);
  unsigned short* Z3  = (unsigned short*)carve((size_t)Nn * 128 * 2);
  unsigned short* h2  = xm;
  unsigned short* W1t = Z2;  // consumed by GEMM1 before GEMM2 writes Z2

  size_t need = (size_t)(p - (char*)d_ws);
  if (ws_size < need) {
    k_sentinel<<<(out_size + 255) / 256, 256, 0, stream>>>((float*)d_out, out_size,
                                                           (float)(ws_size >> 20));
    return;
  }

  // 1) prep
  k_prep<<<8000 + 2048 + 2048 + 4096 + 4096 + 64 + 64 + 63, 256, 0, stream>>>(
      (const float4*)x, (ushort4*)xm, W1l, W1r, W2l, W2r, W3l, W3r, W1t, W2t, W3t, deg, Nn);
  // 2-4) CSR
  k_degree<<<(E + 255) / 256, 256, 0, stream>>>(ei, E, deg);
  k_scan<<<1, 256, 0, stream>>>(deg, rp, cur, Nn);
  k_fill<<<(E + 255) / 256, 256, 0, stream>>>(ei, E, cur, colidx);
  // 5) layer-1 aggregation
  k_agg<<<Nn, 256, 0, stream>>>(xm, rp, colidx);
  // 6) GEMM1 (dual-role)
  k_gemm256d<true, true><<<63 * 16, 512, 0, stream>>>(xm, W1t, b1, h1, Nn, 4096, 1024, 4);
  // 7) GEMM2 (dual-role)
  k_gemm256d<false, false><<<63 * 8, 512, 0, stream>>>(h1, W2t, nullptr, Z2, Nn, 2048, 4096, 3);
  // 8) combine2 -> h2 (256 thr, 2-way parity — r14/r17-validated)
  k_combine2<<<Nn, 256, 0, stream>>>(Z2, rp, colidx, b2, h2);
  // 9) GEMM3
  k_gemm<2, false, false, false><<<dim3(125, 2), 256, 0, stream>>>(h2, nullptr, W3t, nullptr,
                                                                   nullptr, Z3, 128, 1024);
  // 10) combine3 + log_softmax
  k_combine3<<<Nn / 4, 256, 0, stream>>>(Z3, rp, colidx, b3, (float*)d_out);

  (void)n_in; (void)out_size;
}